// Round 9
// baseline (500.665 us; speedup 1.0000x reference)
//
#include <hip/hip_runtime.h>

#define Bb 2
#define Nn 50000
#define Ee 512000
#define DE 128
#define HH 256
#define DO 128
#define TILES 782        // ceil(50000/64)
#define CAP 48           // per-node slot capacity (Poisson(10.24) max deg ~35)
#define NCNT (Bb * Nn)   // 100,000 nodes; cnt[NCNT] is the spill counter
#define SPILL_MAX 65536

typedef __attribute__((ext_vector_type(8))) short short8;
typedef __attribute__((ext_vector_type(4))) float f32x4;

// Agent-scope atomic store: lay down the zeros that later atomicAdds RMW
// (round-3: plain-stored zeros + cross-kernel atomic RMW diverged in replay).
#define ATOMIC_ST(p, v) __hip_atomic_store((p), (v), __ATOMIC_RELAXED, __HIP_MEMORY_SCOPE_AGENT)

// f32 -> bf16 round-to-nearest-even (data has no NaN/Inf)
static __device__ __forceinline__ unsigned short f2bf(float f) {
  union { float f; unsigned int u; } x; x.f = f;
  return (unsigned short)((x.u + 0x7FFFu + ((x.u >> 16) & 1u)) >> 16);
}
// bf16 -> f32
static __device__ __forceinline__ float bf2f(unsigned short h) {
  union { unsigned int u; float f; } x; x.u = ((unsigned int)h) << 16;
  return x.f;
}

// Pre-convert W1/W2 into bf16 MFMA B-fragment order (one dwordx4 per frag).
__global__ void wconv_kernel(const float* __restrict__ W1, const float* __restrict__ W2,
                             unsigned short* __restrict__ w1f, unsigned short* __restrict__ w2f) {
  int t = blockIdx.x * 256 + threadIdx.x;
  if (t < 16 * 8 * 64) {
    int lane = t & 63, ks = (t >> 6) & 7, ct = t >> 9;
    int col = ct * 16 + (lane & 15);
    int k0 = ks * 32 + (lane >> 4) * 8;
    for (int j = 0; j < 8; ++j)
      w1f[t * 8 + j] = f2bf(W1[(k0 + j) * HH + col]);
  }
  if (t < 8 * 8 * 64) {
    int lane = t & 63, ks = (t >> 6) & 7, ct = t >> 9;
    int col = ct * 16 + (lane & 15);
    int k0 = ks * 32 + (lane >> 4) * 8;
    for (int j = 0; j < 8; ++j)
      w2f[t * 8 + j] = f2bf(W2[(k0 + j) * DO + col]);
  }
}

// Zero cnt[0..NCNT] with AGENT-scope atomic stores.
__global__ void zero_cnt_kernel(int* __restrict__ cnt) {
  int i = blockIdx.x * 256 + threadIdx.x;
  if (i <= NCNT) ATOMIC_ST(&cnt[i], 0);
}

// Sequential-read / scattered-full-line-write CSR build: HALF-WAVE PER EDGE.
// Reads the edge row (512B coalesced f32), converts to bf16, writes it to
// padded[node*CAP + pos] (256B aligned, full lines, no RMW). Round-8 showed
// random 512B READS cap at ~2 TB/s; scattered fire-and-forget WRITES replace
// them, and the consumer reads contiguous per-node chunks.
__global__ __launch_bounds__(256) void fill_place_kernel(
    const float4* __restrict__ edge4, const int* __restrict__ recv,
    int* __restrict__ cnt, unsigned short* __restrict__ padded,
    int* __restrict__ spill_node, unsigned short* __restrict__ spill_data) {
  int gtid = blockIdx.x * 256 + threadIdx.x;
  int e = gtid >> 5;                 // grid sized exactly: e < Bb*Ee
  int hl = threadIdx.x & 31;
  int node = ((e >= Ee) ? Nn : 0) + recv[e];

  float4 v = edge4[(long)e * 32 + hl];
  ushort4 o;
  o.x = f2bf(v.x); o.y = f2bf(v.y); o.z = f2bf(v.z); o.w = f2bf(v.w);

  int pos;
  if (hl == 0) pos = atomicAdd(&cnt[node], 1);
  pos = __shfl(pos, threadIdx.x & 32);  // broadcast within half-wave

  if (pos < CAP) {
    reinterpret_cast<ushort4*>(padded)[((long)node * CAP + pos) * 32 + hl] = o;
  } else {  // ~never: P(deg>48 | Poisson(10.24)) ~ 1e-17 per node
    int s;
    if (hl == 0) s = atomicAdd(&cnt[NCNT], 1);
    s = __shfl(s, threadIdx.x & 32);
    if (s < SPILL_MAX) {
      if (hl == 0) spill_node[s] = node;
      reinterpret_cast<ushort4*>(spill_data)[(long)s * 32 + hl] = o;
    }
  }
}

// Fused CSR-gather + MLP: per block, 64 nodes.
// Phase A: node features -> LDS cols 128..255 (bf16, XOR-swizzled).
// Phase B: half-wave per node sums its contiguous padded chunk (deg x 256B,
//          8-deep ILP) in f32 -> LDS cols 0..127. Consecutive nodes read
//          consecutive-ish chunks -> near-streaming (round-7's failure was
//          RANDOM 512B reads at low occupancy; these are contiguous).
// Then GEMM1 (K=256,N=256) -> relu -> h in LDS -> GEMM2 -> out f32.
__global__ __launch_bounds__(256, 2) void mlp_kernel(
    const unsigned short* __restrict__ padded, const int* __restrict__ cnt,
    const int* __restrict__ spill_node, const unsigned short* __restrict__ spill_data,
    const float* __restrict__ node,
    const unsigned short* __restrict__ w1f, const unsigned short* __restrict__ w2f,
    const float* __restrict__ b1, const float* __restrict__ b2,
    float* __restrict__ out) {
  __shared__ __align__(16) char lds[64 * 512];  // 64 rows x 256 cols bf16
  const int tid = threadIdx.x;
  const int lane = tid & 63;
  const int wv = tid >> 6;
  const int blk = blockIdx.x;
  const int b = blk / TILES;
  const int tile = blk - b * TILES;
  const int row0 = tile * 64;
  const int rows = min(64, Nn - row0);
  const ushort4* __restrict__ padded4 = reinterpret_cast<const ushort4*>(padded);

  // ---- Phase A: node features -> LDS cols 128..255 ----
#pragma unroll
  for (int ii = 0; ii < 8; ++ii) {
    int idx = ii * 256 + tid;
    int row = idx >> 5;
    int c4 = idx & 31;
    float4 v = make_float4(0.f, 0.f, 0.f, 0.f);
    if (row < rows)
      v = reinterpret_cast<const float4*>(node)[((long)b * Nn + row0 + row) * 32 + c4];
    ushort4 p;
    p.x = f2bf(v.x); p.y = f2bf(v.y); p.z = f2bf(v.z); p.w = f2bf(v.w);
    int byte = row * 512 + ((256 + c4 * 8) ^ ((row & 7) << 4));
    *reinterpret_cast<ushort4*>(&lds[byte]) = p;
  }

  // ---- Phase B: per-node chunk sum -> LDS cols 0..127 ----
  {
    const int hw = tid >> 5;   // half-wave 0..7, owns rows k*8+hw
    const int hl = tid & 31;   // float4 cols hl*4..hl*4+3 (ushort4 = 8B)
#pragma unroll
    for (int k = 0; k < 8; ++k) {
      int rloc = k * 8 + hw;
      float ax = 0.f, ay = 0.f, az = 0.f, aw = 0.f;
      if (rloc < rows) {
        int g = b * Nn + row0 + rloc;
        int deg = min(cnt[g], CAP);
        const ushort4* base = padded4 + (long)g * CAP * 32 + hl;
        int i = 0;
        for (; i + 8 <= deg; i += 8) {  // 8 independent loads in flight
          ushort4 q0 = base[(i + 0) * 32], q1 = base[(i + 1) * 32];
          ushort4 q2 = base[(i + 2) * 32], q3 = base[(i + 3) * 32];
          ushort4 q4 = base[(i + 4) * 32], q5 = base[(i + 5) * 32];
          ushort4 q6 = base[(i + 6) * 32], q7 = base[(i + 7) * 32];
          ax += (bf2f(q0.x) + bf2f(q1.x)) + (bf2f(q2.x) + bf2f(q3.x)) +
                (bf2f(q4.x) + bf2f(q5.x)) + (bf2f(q6.x) + bf2f(q7.x));
          ay += (bf2f(q0.y) + bf2f(q1.y)) + (bf2f(q2.y) + bf2f(q3.y)) +
                (bf2f(q4.y) + bf2f(q5.y)) + (bf2f(q6.y) + bf2f(q7.y));
          az += (bf2f(q0.z) + bf2f(q1.z)) + (bf2f(q2.z) + bf2f(q3.z)) +
                (bf2f(q4.z) + bf2f(q5.z)) + (bf2f(q6.z) + bf2f(q7.z));
          aw += (bf2f(q0.w) + bf2f(q1.w)) + (bf2f(q2.w) + bf2f(q3.w)) +
                (bf2f(q4.w) + bf2f(q5.w)) + (bf2f(q6.w) + bf2f(q7.w));
        }
        for (; i < deg; ++i) {
          ushort4 q = base[i * 32];
          ax += bf2f(q.x); ay += bf2f(q.y); az += bf2f(q.z); aw += bf2f(q.w);
        }
      }
      ushort4 s;
      s.x = f2bf(ax); s.y = f2bf(ay); s.z = f2bf(az); s.w = f2bf(aw);
      int byte = rloc * 512 + ((hl * 8) ^ ((rloc & 7) << 4));
      *reinterpret_cast<ushort4*>(&lds[byte]) = s;
    }
  }

  // ---- rare spill fix-up (deg > CAP; normally cnt[NCNT]==0) ----
  {
    int sn = min(cnt[NCNT], SPILL_MAX);
    if (sn > 0) {
      const int hw = tid >> 5;
      const int hl = tid & 31;
      for (int k = 0; k < 8; ++k) {
        int rloc = k * 8 + hw;
        if (rloc >= rows) continue;
        int g = b * Nn + row0 + rloc;
        float ax = 0.f, ay = 0.f, az = 0.f, aw = 0.f;
        bool any = false;
        for (int s = 0; s < sn; ++s) {
          if (spill_node[s] == g) {
            ushort4 q = reinterpret_cast<const ushort4*>(spill_data)[(long)s * 32 + hl];
            ax += bf2f(q.x); ay += bf2f(q.y); az += bf2f(q.z); aw += bf2f(q.w);
            any = true;
          }
        }
        if (any) {  // sole owner (hw,hl) of these LDS bytes -> no race
          int byte = rloc * 512 + ((hl * 8) ^ ((rloc & 7) << 4));
          ushort4 q = *reinterpret_cast<ushort4*>(&lds[byte]);
          q.x = f2bf(bf2f(q.x) + ax);
          q.y = f2bf(bf2f(q.y) + ay);
          q.z = f2bf(bf2f(q.z) + az);
          q.w = f2bf(bf2f(q.w) + aw);
          *reinterpret_cast<ushort4*>(&lds[byte]) = q;
        }
      }
    }
  }
  __syncthreads();

  // ---- GEMM1: h = relu(vtin @ W1 + b1) ----
  f32x4 acc[16];
#pragma unroll
  for (int ct = 0; ct < 16; ++ct) acc[ct] = (f32x4){0.f, 0.f, 0.f, 0.f};
  const int arow = wv * 16 + (lane & 15);
  const int abase = arow * 512;
  const int aswz = (arow & 7) << 4;
  const int koff = (lane >> 4) * 16;
#pragma unroll
  for (int ks = 0; ks < 8; ++ks) {
    short8 a = *reinterpret_cast<const short8*>(&lds[abase + ((ks * 64 + koff) ^ aswz)]);
#pragma unroll
    for (int ct = 0; ct < 16; ++ct) {
      short8 bf = *reinterpret_cast<const short8*>(w1f + ((ct * 8 + ks) * 64 + lane) * 8);
      acc[ct] = __builtin_amdgcn_mfma_f32_16x16x32_bf16(a, bf, acc[ct], 0, 0, 0);
    }
  }
  __syncthreads();  // all waves done reading vtin before overwrite

  // ---- bias + relu, write h (bf16, swizzled) ----
  {
    const int colb = lane & 15;
    const int rb = wv * 16 + (lane >> 4) * 4;
#pragma unroll
    for (int ct = 0; ct < 16; ++ct) {
      float bias = b1[ct * 16 + colb];
#pragma unroll
      for (int j = 0; j < 4; ++j) {
        float hv = acc[ct][j] + bias;
        hv = hv > 0.f ? hv : 0.f;
        int row = rb + j;
        int byte = row * 512 + (((ct * 16 + colb) * 2) ^ ((row & 7) << 4));
        *reinterpret_cast<unsigned short*>(&lds[byte]) = f2bf(hv);
      }
    }
  }
  __syncthreads();

  // ---- GEMM2: out = h @ W2 + b2 ----
  f32x4 acc2[8];
#pragma unroll
  for (int ct = 0; ct < 8; ++ct) acc2[ct] = (f32x4){0.f, 0.f, 0.f, 0.f};
#pragma unroll
  for (int ks = 0; ks < 8; ++ks) {
    short8 a = *reinterpret_cast<const short8*>(&lds[abase + ((ks * 64 + koff) ^ aswz)]);
#pragma unroll
    for (int ct = 0; ct < 8; ++ct) {
      short8 bf = *reinterpret_cast<const short8*>(w2f + ((ct * 8 + ks) * 64 + lane) * 8);
      acc2[ct] = __builtin_amdgcn_mfma_f32_16x16x32_bf16(a, bf, acc2[ct], 0, 0, 0);
    }
  }
  {
    const int colb = lane & 15;
    const int rb = wv * 16 + (lane >> 4) * 4;
#pragma unroll
    for (int ct = 0; ct < 8; ++ct) {
      float bias = b2[ct * 16 + colb];
#pragma unroll
      for (int j = 0; j < 4; ++j) {
        int r = rb + j;
        if (r < rows)
          out[((long)b * Nn + row0 + r) * DO + ct * 16 + colb] = acc2[ct][j] + bias;
      }
    }
  }
}

extern "C" void kernel_launch(void* const* d_in, const int* in_sizes, int n_in,
                              void* d_out, int out_size, void* d_ws, size_t ws_size,
                              hipStream_t stream) {
  const float* edge = (const float*)d_in[0];
  const float* node = (const float*)d_in[1];
  const float* W1   = (const float*)d_in[2];
  const float* b1   = (const float*)d_in[3];
  const float* W2   = (const float*)d_in[4];
  const float* b2   = (const float*)d_in[5];
  const int*   recv = (const int*)d_in[6];
  float* out = (float*)d_out;

  char* ws = (char*)d_ws;
  size_t off = 0;
  unsigned short* w1f = (unsigned short*)(ws + off); off += 131072;
  unsigned short* w2f = (unsigned short*)(ws + off); off += 65536;
  int* cnt = (int*)(ws + off); off += 400016;                       // (NCNT+1)*4 padded
  int* spill_node = (int*)(ws + off); off += SPILL_MAX * 4;         // 262,144
  unsigned short* spill_data = (unsigned short*)(ws + off); off += (size_t)SPILL_MAX * DE * 2;  // 16.8 MB
  unsigned short* padded = (unsigned short*)(ws + off);             // NCNT*CAP*DE*2 = 1.2288 GB

  wconv_kernel<<<32, 256, 0, stream>>>(W1, W2, w1f, w2f);
  zero_cnt_kernel<<<(NCNT + 256) / 256, 256, 0, stream>>>(cnt);
  fill_place_kernel<<<Bb * Ee / 8, 256, 0, stream>>>((const float4*)edge, recv, cnt,
                                                     padded, spill_node, spill_data);
  mlp_kernel<<<Bb * TILES, 256, 0, stream>>>(padded, cnt, spill_node, spill_data,
                                             node, w1f, w2f, b1, b2, out);
}

// Round 10
// 452.383 us; speedup vs baseline: 1.1067x; 1.1067x over previous
//
#include <hip/hip_runtime.h>

#define Bb 2
#define Nn 50000
#define Ee 512000
#define DE 128
#define HH 256
#define DO 128
#define TILES 782        // ceil(50000/64)
#define CAP 32           // per-node slot capacity; P(deg>32|Poisson(10.24)) ~ 3e-8/node
#define NCNT (Bb * Nn)   // 100,000 nodes; cnt[NCNT] is the spill counter
#define SPILL_MAX 65536

typedef __attribute__((ext_vector_type(8))) short short8;
typedef __attribute__((ext_vector_type(4))) float f32x4;

// Agent-scope atomic store: lay down the zeros that later atomicAdds RMW
// (round-3: plain-stored zeros + cross-kernel atomic RMW diverged in replay).
#define ATOMIC_ST(p, v) __hip_atomic_store((p), (v), __ATOMIC_RELAXED, __HIP_MEMORY_SCOPE_AGENT)

// f32 -> bf16 round-to-nearest-even (data has no NaN/Inf)
static __device__ __forceinline__ unsigned short f2bf(float f) {
  union { float f; unsigned int u; } x; x.f = f;
  return (unsigned short)((x.u + 0x7FFFu + ((x.u >> 16) & 1u)) >> 16);
}
// bf16 -> f32
static __device__ __forceinline__ float bf2f(unsigned short h) {
  union { unsigned int u; float f; } x; x.u = ((unsigned int)h) << 16;
  return x.f;
}
// accumulate 8 bf16 lanes into f32 accumulators
static __device__ __forceinline__ void add8(float* a, short8 q) {
#pragma unroll
  for (int j = 0; j < 8; ++j) a[j] += bf2f((unsigned short)q[j]);
}

// Pre-convert W1/W2 into bf16 MFMA B-fragment order (one dwordx4 per frag).
__global__ void wconv_kernel(const float* __restrict__ W1, const float* __restrict__ W2,
                             unsigned short* __restrict__ w1f, unsigned short* __restrict__ w2f) {
  int t = blockIdx.x * 256 + threadIdx.x;
  if (t < 16 * 8 * 64) {
    int lane = t & 63, ks = (t >> 6) & 7, ct = t >> 9;
    int col = ct * 16 + (lane & 15);
    int k0 = ks * 32 + (lane >> 4) * 8;
    for (int j = 0; j < 8; ++j)
      w1f[t * 8 + j] = f2bf(W1[(k0 + j) * HH + col]);
  }
  if (t < 8 * 8 * 64) {
    int lane = t & 63, ks = (t >> 6) & 7, ct = t >> 9;
    int col = ct * 16 + (lane & 15);
    int k0 = ks * 32 + (lane >> 4) * 8;
    for (int j = 0; j < 8; ++j)
      w2f[t * 8 + j] = f2bf(W2[(k0 + j) * DO + col]);
  }
}

// Zero cnt[0..NCNT] with AGENT-scope atomic stores.
__global__ void zero_cnt_kernel(int* __restrict__ cnt) {
  int i = blockIdx.x * 256 + threadIdx.x;
  if (i <= NCNT) ATOMIC_ST(&cnt[i], 0);
}

// Sequential-read / scattered-full-line-write CSR build: HALF-WAVE PER EDGE.
// Reads the edge row (512B coalesced f32), converts to bf16, writes it to
// padded[node*CAP + pos] (256B aligned full lines, fire-and-forget, no RMW).
// Round-8: random 512B READS cap ~2 TB/s; this converts them into scattered
// WRITES (~2x cheaper, round-9 measured) + contiguous reads for the consumer.
__global__ __launch_bounds__(256) void fill_place_kernel(
    const float4* __restrict__ edge4, const int* __restrict__ recv,
    int* __restrict__ cnt, unsigned short* __restrict__ padded,
    int* __restrict__ spill_node, unsigned short* __restrict__ spill_data) {
  int gtid = blockIdx.x * 256 + threadIdx.x;
  int e = gtid >> 5;                 // grid sized exactly: e < Bb*Ee
  int hl = threadIdx.x & 31;
  int node = ((e >= Ee) ? Nn : 0) + recv[e];

  float4 v = edge4[(long)e * 32 + hl];
  ushort4 o;
  o.x = f2bf(v.x); o.y = f2bf(v.y); o.z = f2bf(v.z); o.w = f2bf(v.w);

  int pos;
  if (hl == 0) pos = atomicAdd(&cnt[node], 1);
  pos = __shfl(pos, threadIdx.x & 32);  // broadcast within half-wave

  if (pos < CAP) {
    reinterpret_cast<ushort4*>(padded)[((long)node * CAP + pos) * 32 + hl] = o;
  } else {  // ~never (P ~ 3e-8 per node)
    int s;
    if (hl == 0) s = atomicAdd(&cnt[NCNT], 1);
    s = __shfl(s, threadIdx.x & 32);
    if (s < SPILL_MAX) {
      if (hl == 0) spill_node[s] = node;
      reinterpret_cast<ushort4*>(spill_data)[(long)s * 32 + hl] = o;
    }
  }
}

// High-occupancy CSR reduce: 16-LANE GROUP PER NODE, lane ql owns bf16 cols
// ql*8..ql*8+7 (16B loads). Each node's chunk is CONTIGUOUS (deg x 256B),
// read 4-deep. No LDS, low VGPR -> 8 waves/SIMD (round-7/9 lesson: the
// latency-bound phase needs its own high-occupancy kernel). Output bf16 aggb.
__global__ __launch_bounds__(256, 8) void csr_sum_kernel(
    const unsigned short* __restrict__ padded, const int* __restrict__ cnt,
    const int* __restrict__ spill_node, const unsigned short* __restrict__ spill_data,
    unsigned short* __restrict__ aggb) {
  int grp = (blockIdx.x * 256 + threadIdx.x) >> 4;  // node id
  int ql = threadIdx.x & 15;
  if (grp >= NCNT) return;
  int deg0 = cnt[grp];
  int deg = min(deg0, CAP);
  const short8* base = reinterpret_cast<const short8*>(padded + (long)grp * CAP * DE) + ql;

  float a[8];
#pragma unroll
  for (int j = 0; j < 8; ++j) a[j] = 0.f;

  int i = 0;
  for (; i + 4 <= deg; i += 4) {  // 4 independent 256B-line loads in flight
    short8 q0 = base[(i + 0) * 16];
    short8 q1 = base[(i + 1) * 16];
    short8 q2 = base[(i + 2) * 16];
    short8 q3 = base[(i + 3) * 16];
    add8(a, q0); add8(a, q1); add8(a, q2); add8(a, q3);
  }
  for (; i < deg; ++i) add8(a, base[i * 16]);

  if (deg0 > CAP) {  // dormant overflow path
    int sn = min(cnt[NCNT], SPILL_MAX);
    for (int s = 0; s < sn; ++s)
      if (spill_node[s] == grp)
        add8(a, reinterpret_cast<const short8*>(spill_data + (long)s * DE)[ql]);
  }

  short8 o;
#pragma unroll
  for (int j = 0; j < 8; ++j) o[j] = (short)f2bf(a[j]);
  reinterpret_cast<short8*>(aggb)[(long)grp * 16 + ql] = o;
}

// MLP (round-8-proven): per block, 64 nodes. vtin=[aggb(bf16)|node(f32->bf16)]
// in LDS (XOR-swizzled), GEMM1 -> relu -> h in LDS -> GEMM2 -> out f32.
__global__ __launch_bounds__(256, 2) void mlp_kernel(
    const unsigned short* __restrict__ aggb, const float* __restrict__ node,
    const unsigned short* __restrict__ w1f, const unsigned short* __restrict__ w2f,
    const float* __restrict__ b1, const float* __restrict__ b2,
    float* __restrict__ out) {
  __shared__ __align__(16) char lds[64 * 512];  // 64 rows x 256 cols bf16
  const int tid = threadIdx.x;
  const int lane = tid & 63;
  const int wv = tid >> 6;
  const int blk = blockIdx.x;
  const int b = blk / TILES;
  const int tile = blk - b * TILES;
  const int row0 = tile * 64;
  const int rows = min(64, Nn - row0);

  // ---- stage vtin: agg half is already bf16; node half converts ----
#pragma unroll
  for (int ii = 0; ii < 8; ++ii) {  // cols 0..127 from aggb
    int idx = ii * 256 + tid;
    int row = idx >> 5;
    int c4 = idx & 31;
    ushort4 p = make_ushort4(0, 0, 0, 0);
    if (row < rows)
      p = reinterpret_cast<const ushort4*>(aggb)[((long)b * Nn + row0 + row) * 32 + c4];
    int byte = row * 512 + ((c4 * 8) ^ ((row & 7) << 4));
    *reinterpret_cast<ushort4*>(&lds[byte]) = p;
  }
#pragma unroll
  for (int ii = 0; ii < 8; ++ii) {  // cols 128..255 from node_data
    int idx = ii * 256 + tid;
    int row = idx >> 5;
    int c4 = idx & 31;
    float4 v = make_float4(0.f, 0.f, 0.f, 0.f);
    if (row < rows)
      v = reinterpret_cast<const float4*>(node)[((long)b * Nn + row0 + row) * 32 + c4];
    ushort4 p;
    p.x = f2bf(v.x); p.y = f2bf(v.y); p.z = f2bf(v.z); p.w = f2bf(v.w);
    int byte = row * 512 + ((256 + c4 * 8) ^ ((row & 7) << 4));
    *reinterpret_cast<ushort4*>(&lds[byte]) = p;
  }
  __syncthreads();

  // ---- GEMM1: h = relu(vtin @ W1 + b1) ----
  f32x4 acc[16];
#pragma unroll
  for (int ct = 0; ct < 16; ++ct) acc[ct] = (f32x4){0.f, 0.f, 0.f, 0.f};
  const int arow = wv * 16 + (lane & 15);
  const int abase = arow * 512;
  const int aswz = (arow & 7) << 4;
  const int koff = (lane >> 4) * 16;
#pragma unroll
  for (int ks = 0; ks < 8; ++ks) {
    short8 a = *reinterpret_cast<const short8*>(&lds[abase + ((ks * 64 + koff) ^ aswz)]);
#pragma unroll
    for (int ct = 0; ct < 16; ++ct) {
      short8 bf = *reinterpret_cast<const short8*>(w1f + ((ct * 8 + ks) * 64 + lane) * 8);
      acc[ct] = __builtin_amdgcn_mfma_f32_16x16x32_bf16(a, bf, acc[ct], 0, 0, 0);
    }
  }
  __syncthreads();  // all waves done reading vtin before overwrite

  // ---- bias + relu, write h (bf16, swizzled) ----
  {
    const int colb = lane & 15;
    const int rb = wv * 16 + (lane >> 4) * 4;
#pragma unroll
    for (int ct = 0; ct < 16; ++ct) {
      float bias = b1[ct * 16 + colb];
#pragma unroll
      for (int j = 0; j < 4; ++j) {
        float hv = acc[ct][j] + bias;
        hv = hv > 0.f ? hv : 0.f;
        int row = rb + j;
        int byte = row * 512 + (((ct * 16 + colb) * 2) ^ ((row & 7) << 4));
        *reinterpret_cast<unsigned short*>(&lds[byte]) = f2bf(hv);
      }
    }
  }
  __syncthreads();

  // ---- GEMM2: out = h @ W2 + b2 ----
  f32x4 acc2[8];
#pragma unroll
  for (int ct = 0; ct < 8; ++ct) acc2[ct] = (f32x4){0.f, 0.f, 0.f, 0.f};
#pragma unroll
  for (int ks = 0; ks < 8; ++ks) {
    short8 a = *reinterpret_cast<const short8*>(&lds[abase + ((ks * 64 + koff) ^ aswz)]);
#pragma unroll
    for (int ct = 0; ct < 8; ++ct) {
      short8 bf = *reinterpret_cast<const short8*>(w2f + ((ct * 8 + ks) * 64 + lane) * 8);
      acc2[ct] = __builtin_amdgcn_mfma_f32_16x16x32_bf16(a, bf, acc2[ct], 0, 0, 0);
    }
  }
  {
    const int colb = lane & 15;
    const int rb = wv * 16 + (lane >> 4) * 4;
#pragma unroll
    for (int ct = 0; ct < 8; ++ct) {
      float bias = b2[ct * 16 + colb];
#pragma unroll
      for (int j = 0; j < 4; ++j) {
        int r = rb + j;
        if (r < rows)
          out[((long)b * Nn + row0 + r) * DO + ct * 16 + colb] = acc2[ct][j] + bias;
      }
    }
  }
}

extern "C" void kernel_launch(void* const* d_in, const int* in_sizes, int n_in,
                              void* d_out, int out_size, void* d_ws, size_t ws_size,
                              hipStream_t stream) {
  const float* edge = (const float*)d_in[0];
  const float* node = (const float*)d_in[1];
  const float* W1   = (const float*)d_in[2];
  const float* b1   = (const float*)d_in[3];
  const float* W2   = (const float*)d_in[4];
  const float* b2   = (const float*)d_in[5];
  const int*   recv = (const int*)d_in[6];
  float* out = (float*)d_out;

  char* ws = (char*)d_ws;
  size_t off = 0;
  unsigned short* w1f = (unsigned short*)(ws + off); off += 131072;
  unsigned short* w2f = (unsigned short*)(ws + off); off += 65536;
  int* cnt = (int*)(ws + off); off += 400016;                       // (NCNT+1)*4 padded
  int* spill_node = (int*)(ws + off); off += SPILL_MAX * 4;         // 262,144
  unsigned short* spill_data = (unsigned short*)(ws + off); off += (size_t)SPILL_MAX * DE * 2;  // 16.8 MB
  unsigned short* aggb = (unsigned short*)(ws + off); off += (size_t)NCNT * DE * 2;  // 25.6 MB
  unsigned short* padded = (unsigned short*)(ws + off);             // NCNT*CAP*DE*2 = 819.2 MB

  wconv_kernel<<<32, 256, 0, stream>>>(W1, W2, w1f, w2f);
  zero_cnt_kernel<<<(NCNT + 256) / 256, 256, 0, stream>>>(cnt);
  fill_place_kernel<<<Bb * Ee / 8, 256, 0, stream>>>((const float4*)edge, recv, cnt,
                                                     padded, spill_node, spill_data);
  csr_sum_kernel<<<NCNT * 16 / 256, 256, 0, stream>>>(padded, cnt, spill_node,
                                                      spill_data, aggb);
  mlp_kernel<<<Bb * TILES, 256, 0, stream>>>(aggb, node, w1f, w2f, b1, b2, out);
}